// Round 9
// baseline (159.118 us; speedup 1.0000x reference)
//
#include <hip/hip_runtime.h>

typedef _Float16 f16x8  __attribute__((ext_vector_type(8)));
typedef _Float16 h2v    __attribute__((ext_vector_type(2)));
typedef float    f32x16 __attribute__((ext_vector_type(16)));
typedef unsigned u32x16 __attribute__((ext_vector_type(16)));

#define NSTEP  42
#define NCHUNK 84
#define PSTR   36      // prep LDS row stride (floats): 144B rows, b128-aligned

// ---------------------------------------------------------------------------
// Step tables (verified R2-R8)
// ---------------------------------------------------------------------------
__host__ __device__ constexpr int stepDA(int s){
  return s < 4 ? 2*s : s < 12 ? 2*(s-4) : s < 24 ? 2*(s-12) : s < 40 ? 2*(s-24) : -1;
}
__host__ __device__ constexpr int stepDB(int s){
  return s < 40 ? stepDA(s) + 1 : -1;
}
__host__ __device__ constexpr int stepEA(int s){
  return s < 4 ? 0 : s < 12 ? 8 : s < 24 ? 16 : s < 40 ? 24 : (s == 40 ? 0 : 16);
}
__host__ __device__ constexpr int stepEB(int s){
  return s < 40 ? stepEA(s) : (s == 40 ? 8 : 24);
}

__device__ inline unsigned short f2h(float f){
  _Float16 h = (_Float16)f;
  unsigned short u; __builtin_memcpy(&u, &h, 2);
  return u;
}
__device__ inline unsigned pkmulh2(unsigned a, unsigned b){
  h2v x, y; __builtin_memcpy(&x, &a, 4); __builtin_memcpy(&y, &b, 4);
  h2v z = x * y;
  unsigned r; __builtin_memcpy(&r, &z, 4);
  return r;
}
__device__ inline unsigned pkrtz(float lo, float hi){
  auto p = __builtin_amdgcn_cvt_pkrtz(lo, hi);
  unsigned u; __builtin_memcpy(&u, &p, 4);
  return u;
}
__device__ inline float dot4(float4 a, float4 b){
  return a.x*b.x + a.y*b.y + a.z*b.z + a.w*b.w;
}

// Build B-fragments (k 0..15 -> b1, k 16..31 -> b2) for a symmetric matrix
// held in verified C-layout regs (col=lane&31, row=(r&3)+8*(r>>2)+4*h).
__device__ inline void bfrags(const f32x16& s, int h, f16x8& b1, f16x8& b2){
  float xo[16];
  #pragma unroll
  for (int j = 0; j < 16; ++j) xo[j] = __shfl_xor(s[j], 32);
  unsigned u[8];
  float e[8];
  #pragma unroll
  for (int j = 0; j < 4; ++j){
    e[j]   = h ? xo[4+j] : s[j];
    e[4+j] = h ? s[4+j]  : xo[j];
  }
  u[0] = pkrtz(e[0],e[1]); u[1] = pkrtz(e[2],e[3]);
  u[2] = pkrtz(e[4],e[5]); u[3] = pkrtz(e[6],e[7]);
  #pragma unroll
  for (int j = 0; j < 4; ++j){
    e[j]   = h ? xo[12+j] : s[8+j];
    e[4+j] = h ? s[12+j]  : xo[8+j];
  }
  u[4] = pkrtz(e[0],e[1]); u[5] = pkrtz(e[2],e[3]);
  u[6] = pkrtz(e[4],e[5]); u[7] = pkrtz(e[6],e[7]);
  __builtin_memcpy(&b1, &u[0], 16);
  __builtin_memcpy(&b2, &u[4], 16);
}

// A-fragments for matrix in LDS (row-major, PSTR stride): lane row = c.
__device__ inline void afrags(const float* Ml, int c, int h, f16x8& a1, f16x8& a2){
  unsigned u[8];
  #pragma unroll
  for (int jj = 0; jj < 4; ++jj){
    float2 v1 = *(const float2*)&Ml[c*PSTR + h*8 + 2*jj];
    float2 v2 = *(const float2*)&Ml[c*PSTR + 16 + h*8 + 2*jj];
    u[jj]   = pkrtz(v1.x, v1.y);
    u[4+jj] = pkrtz(v2.x, v2.y);
  }
  __builtin_memcpy(&a1, &u[0], 16);
  __builtin_memcpy(&a2, &u[4], 16);
}

// ---------------------------------------------------------------------------
// Prep v7 (byte-identical to R8): one wave per mixture, MFMA Newton-Schulz,
// zero barriers. Gershgorin bound; X1 = c(2I-cS); 5x NS; tau-series logdet.
// ---------------------------------------------------------------------------
__global__ __launch_bounds__(64) void gmm_prep(
    const float* __restrict__ mus, const float* __restrict__ sigmas,
    const float* __restrict__ phis, unsigned short* __restrict__ Bws,
    float* __restrict__ cstw)
{
  __shared__ alignas(16) float Sl[32*PSTR];
  __shared__ alignas(16) float Xl[32*PSTR];
  __shared__ float gld[32];

  const int k    = blockIdx.x;
  const int lane = threadIdx.x;
  const int c    = lane & 31;
  const int h    = lane >> 5;

  {
    const float4* sg = (const float4*)(sigmas + (size_t)k * 1024);
    #pragma unroll
    for (int q = 0; q < 4; ++q){
      int idx = lane + 64*q;
      float4 v = sg[idx];
      int r  = idx >> 3;
      int c0 = (idx & 7) * 4;
      *(float4*)&Sl[r*PSTR + c0] = v;
    }
  }

  float rs = 0.f;
  #pragma unroll
  for (int q = 0; q < 8; ++q){
    float4 v = *(const float4*)&Sl[c*PSTR + q*4];
    rs += fabsf(v.x) + fabsf(v.y) + fabsf(v.z) + fabsf(v.w);
  }
  #pragma unroll
  for (int md = 1; md <= 16; md <<= 1)
    rs = fmaxf(rs, __shfl_xor(rs, md));
  const float cg = 1.f / rs;

  f16x8 sA1, sA2;
  afrags(Sl, c, h, sA1, sA2);

  f32x16 Xc, R0;
  float p1 = 0.f, p2 = 0.f;
  #pragma unroll
  for (int r = 0; r < 16; ++r){
    int row  = (r & 3) + 8 * (r >> 2) + 4 * h;
    float sv = Sl[row*PSTR + c];
    float iv = (row == c) ? 1.f : 0.f;
    float r0 = iv - cg * sv;
    R0[r] = r0;
    Xc[r] = cg * (2.f * iv - cg * sv);
    p1 += (row == c) ? r0 : 0.f;
    p2 += r0 * r0;
    Xl[row*PSTR + c] = Xc[r];
  }

  f32x16 R1, R2, R3;
  float p3 = 0.f, p4 = 0.f, p5 = 0.f, p6 = 0.f, p8 = 0.f;
  float p9 = 0.f, p10 = 0.f, p12 = 0.f, p16 = 0.f;

  #pragma unroll
  for (int it = 0; it < 5; ++it){
    f16x8 xb1, xb2;
    bfrags(Xc, h, xb1, xb2);
    f32x16 Yc;
    #pragma unroll
    for (int i = 0; i < 16; ++i) Yc[i] = 0.f;
    Yc = __builtin_amdgcn_mfma_f32_32x32x16_f16(sA1, xb1, Yc, 0, 0, 0);
    Yc = __builtin_amdgcn_mfma_f32_32x32x16_f16(sA2, xb2, Yc, 0, 0, 0);

    f32x16 Rc;
    #pragma unroll
    for (int r = 0; r < 16; ++r){
      int row = (r & 3) + 8 * (r >> 2) + 4 * h;
      Rc[r] = ((row == c) ? 1.f : 0.f) - Yc[r];
    }

    if (it == 0){
      #pragma unroll
      for (int r = 0; r < 16; ++r){ p3 += R0[r]*Rc[r]; p4 += Rc[r]*Rc[r]; }
      R1 = Rc;
    } else if (it == 1){
      #pragma unroll
      for (int r = 0; r < 16; ++r){ p5 += R0[r]*Rc[r]; p6 += R1[r]*Rc[r]; p8 += Rc[r]*Rc[r]; }
      R2 = Rc;
    } else if (it == 2){
      #pragma unroll
      for (int r = 0; r < 16; ++r){
        p9 += R0[r]*Rc[r]; p10 += R1[r]*Rc[r]; p12 += R2[r]*Rc[r]; p16 += Rc[r]*Rc[r];
      }
      R3 = Rc;
    }
    (void)R3;

    f16x8 xa1, xa2, rb1, rb2;
    afrags(Xl, c, h, xa1, xa2);
    bfrags(Rc, h, rb1, rb2);
    f32x16 Xn = Xc;
    Xn = __builtin_amdgcn_mfma_f32_32x32x16_f16(xa1, rb1, Xn, 0, 0, 0);
    Xn = __builtin_amdgcn_mfma_f32_32x32x16_f16(xa2, rb2, Xn, 0, 0, 0);
    #pragma unroll
    for (int r = 0; r < 16; ++r){
      int row = (r & 3) + 8 * (r >> 2) + 4 * h;
      Xl[row*PSTR + c] = Xn[r];
    }
    Xc = Xn;
  }

  float pp[11] = {p1,p2,p3,p4,p5,p6,p8,p9,p10,p12,p16};
  #pragma unroll
  for (int i = 0; i < 11; ++i){
    float v = pp[i];
    #pragma unroll
    for (int md = 1; md <= 32; md <<= 1) v += __shfl_xor(v, md);
    pp[i] = v;
  }
  const float t1 = pp[0], t2 = pp[1], t3 = pp[2], t4 = pp[3], t5 = pp[4];
  const float t6 = pp[5], t8 = pp[6], t9 = pp[7], t10 = pp[8], t12 = pp[9];

  const float4* mp = (const float4*)(mus + (size_t)k * 32);
  float g = 0.f;
  #pragma unroll
  for (int q = 0; q < 8; ++q)
    g += dot4(*(const float4*)&Xl[c*PSTR + q*4], mp[q]);
  if (h == 0) gld[c] = g;
  float hh = g * mus[(size_t)k * 32 + c];
  #pragma unroll
  for (int md = 1; md <= 16; md <<= 1) hh += __shfl_xor(hh, md);

  if (lane == 0){
    float t7  = sqrtf(fmaxf(t6 * t8, 0.f));
    float t11 = sqrtf(fmaxf(t10 * t12, 0.f));
    float rg  = (t10 > 1e-30f) ? sqrtf(t12 / t10) : 0.f;
    rg = fminf(rg, 0.95f);
    float tail = t12 * rg / (13.f * (1.f - rg));
    float ser = t1 + t2*0.5f + t3*(1.f/3.f) + t4*0.25f + t5*0.2f
              + t6*(1.f/6.f) + t7*(1.f/7.f) + t8*0.125f + t9*(1.f/9.f)
              + t10*0.1f + t11*(1.f/11.f) + t12*(1.f/12.f) + tail;
    float logdet = -ser - 32.f * logf(cg);
    cstw[k] = -logf(phis[k]) + 0.5f * (32.f * 1.8378770664093453f + logdet) + 0.5f * hh;
  }

  for (int ci = lane; ci < NCHUNK; ci += 64){
    int s2 = ci >> 1, hb = ci & 1;
    int d  = hb ? stepDB(s2) : stepDA(s2);
    int e0 = hb ? stepEB(s2) : stepEA(s2);
    unsigned short u8[8];
    for (int j = 0; j < 8; ++j){
      int e = e0 + j;
      float v;
      if (d < 0)       v = -gld[e];
      else if (e < d)  v = 0.f;
      else if (e == d) v = 0.5f * Xl[d*PSTR + d];
      else             v = Xl[d*PSTR + e];
      u8[j] = f2h(v);
    }
    uint4 pk; __builtin_memcpy(&pk, u8, 16);
    ((uint4*)Bws)[ci * 32 + k] = pk;
  }
}

// ---------------------------------------------------------------------------
// Main v5: persistent 768-block grid (exactly co-resident capacity at 3
// blocks/CU), grid-stride loop over 256-row tiles -> no straggler generation;
// ldsB staged ONCE per block and reused across tiles (read-only in loop).
// Tile body identical to the verified R5/R8 template-unrolled code.
// ---------------------------------------------------------------------------
union AF8 { unsigned u[4]; f16x8 v; };

template<int S>
__device__ inline void gstep(const f16x8* __restrict__ Bf, int lane, int h,
                             unsigned sel, const u32x16& xu, f32x16& acc)
{
  f16x8 b = Bf[(S << 6) + lane];
  AF8 a;
  if constexpr (S < 40){
    constexpr int p = stepDA(S) >> 1;
    constexpr int e = stepEA(S) >> 1;
    unsigned m = __builtin_amdgcn_perm(xu[p], xu[p], sel);
    a.u[0] = pkmulh2(m, xu[e + 0]);
    a.u[1] = pkmulh2(m, xu[e + 1]);
    a.u[2] = pkmulh2(m, xu[e + 2]);
    a.u[3] = pkmulh2(m, xu[e + 3]);
  } else {
    constexpr int ea = stepEA(S) >> 1;
    constexpr int eb = stepEB(S) >> 1;
    a.u[0] = h ? xu[eb + 0] : xu[ea + 0];
    a.u[1] = h ? xu[eb + 1] : xu[ea + 1];
    a.u[2] = h ? xu[eb + 2] : xu[ea + 2];
    a.u[3] = h ? xu[eb + 3] : xu[ea + 3];
  }
  acc = __builtin_amdgcn_mfma_f32_32x32x16_f16(a.v, b, acc, 0, 0, 0);
}

template<int S>
__device__ inline void gsteps(const f16x8* __restrict__ Bf, int lane, int h,
                              unsigned sel, const u32x16& xu, f32x16& acc)
{
  if constexpr (S < NSTEP){
    gstep<S>(Bf, lane, h, sel, xu, acc);
    gsteps<S + 1>(Bf, lane, h, sel, xu, acc);
  }
}

__global__ __launch_bounds__(512, 4) void gmm_main(
    const float* __restrict__ X, const unsigned short* __restrict__ Bws,
    const float* __restrict__ cstg, float* __restrict__ out, int N)
{
  __shared__ uint4 ldsB[NSTEP * 64];   // 43008 B

  const int tid  = threadIdx.x;
  const int lane = tid & 63;
  const int wv   = tid >> 6;
  const int h    = lane >> 5;
  const int c32  = lane & 31;

  // stage B fragments once; read-only for the rest of the kernel
  const uint4* Bg = (const uint4*)Bws;
  for (int i = tid; i < NSTEP * 64; i += 512) ldsB[i] = Bg[i];

  const unsigned sel = h ? 0x03020302u : 0x01000100u;
  const float cc = cstg[c32];
  __syncthreads();

  const int NT = (N + 255) >> 8;       // 256-row tiles
  for (int t = blockIdx.x; t < NT; t += gridDim.x){
    const int blockRow = t * 256;
    const int rowi = blockRow + wv * 32 + c32;
    const int rowc = rowi < N ? rowi : N - 1;

    u32x16 xu;
    {
      const float4* xp = (const float4*)(X + (size_t)rowc * 32);
      #pragma unroll
      for (int q = 0; q < 8; ++q){
        float4 v = xp[q];
        xu[q*2+0] = pkrtz(v.x, v.y);
        xu[q*2+1] = pkrtz(v.z, v.w);
      }
    }

    f32x16 acc;
    #pragma unroll
    for (int i = 0; i < 16; ++i) acc[i] = 0.f;

    gsteps<0>((const f16x8*)ldsB, lane, h, sel, xu, acc);

    float nll[16], mx[16];
    #pragma unroll
    for (int r = 0; r < 16; ++r){
      float nv = acc[r] + cc;
      nll[r] = nv; mx[r] = nv;
    }
    #pragma unroll
    for (int md = 1; md <= 16; md <<= 1){
      #pragma unroll
      for (int r = 0; r < 16; ++r)
        mx[r] = fmaxf(mx[r], __shfl_xor(mx[r], md));
    }
    const int rowBase = blockRow + wv * 32;
    #pragma unroll
    for (int r = 0; r < 16; ++r){
      int row = (r & 3) + 8 * (r >> 2) + 4 * h;
      int n = rowBase + row;
      if (n < N) out[(size_t)n * 32 + c32] = nll[r] * __builtin_amdgcn_rcpf(mx[r]);
    }
  }
}

extern "C" void kernel_launch(void* const* d_in, const int* in_sizes, int n_in,
                              void* d_out, int out_size, void* d_ws, size_t ws_size,
                              hipStream_t stream)
{
  const float* X      = (const float*)d_in[0];
  const float* mus    = (const float*)d_in[1];
  const float* sigmas = (const float*)d_in[2];
  const float* phis   = (const float*)d_in[3];
  float* out = (float*)d_out;
  const int N = in_sizes[0] / 32;

  unsigned short* Bws = (unsigned short*)d_ws;
  float* cstw = (float*)((char*)d_ws + NCHUNK * 256 * 2);   // +43008 B

  gmm_prep<<<32, 64, 0, stream>>>(mus, sigmas, phis, Bws, cstw);

  const int NT = (N + 255) / 256;
  const int nb = NT < 768 ? NT : 768;   // exactly co-resident (3 blocks/CU)
  gmm_main<<<nb, 512, 0, stream>>>(X, Bws, cstw, out, N);
}